// Round 7
// baseline (567.407 us; speedup 1.0000x reference)
//
#include <hip/hip_runtime.h>
#include <hip/hip_bf16.h>
#include <math.h>

#define HID   128
#define NNODE 50000
#define NEDGE 800000
#define EB    64
#define PX    136   // intermediate pitch (shorts) = 68 dwords = 34 float2
#define PN    392   // node featA pitch (shorts): [h | agg_hi | agg_lo]

typedef __attribute__((ext_vector_type(8))) short short8;
typedef __attribute__((ext_vector_type(4))) float f32x4;

__device__ __forceinline__ float2 silu2(float x, float y) {
    return make_float2(x * __builtin_amdgcn_rcpf(1.0f + __expf(-x)),
                       y * __builtin_amdgcn_rcpf(1.0f + __expf(-y)));
}
__device__ __forceinline__ unsigned int pkbf(float2 v) {   // packed RNE f32x2 -> bf16x2
    __hip_bfloat162 b2 = __float22bfloat162_rn(v);
    return *(unsigned int*)&b2;
}
__device__ __forceinline__ unsigned short f2bf(float f) {  // scalar RNE
    unsigned int u = __float_as_uint(f);
    u += 0x7FFFu + ((u >> 16) & 1u);
    return (unsigned short)(u >> 16);
}
__device__ __forceinline__ float bf2f(unsigned short s) {
    return __uint_as_float(((unsigned int)s) << 16);
}
// physical col p (128-wide pair-interleaved buffer) -> logical col
__device__ __forceinline__ int permk(int p) {
    return (p & ~31) | ((p & 31) >> 1) | ((p & 1) << 4);
}

// ws layout (bytes)
#define WS_WRN  262144
#define WS_WEA  262656
#define WS_AB   263168
#define WS_DEG  25863168
#define WS_ROW  26063168
#define WS_CUR  26263168
#define WS_BSUM 26463168
#define WS_PERM 26464192

// ------------------------------------------------------------------ prep
// weight frags: preW (eW1 col-permuted, K=128 N=256) @0, eW2f @4096u, cW1f @6144u,
// nW1f @8192u (mode2), nW2f @14336u; wrn/wea fp32; zero agg; pos copy; zero deg.
__global__ void egnn_prep(const float* eW1, const float* eW2, const float* cW1,
                          const float* nW1, const float* nW2, const float* pos,
                          short* wsw, float* wrn, float* wea, int* deg, float* out)
{
    int g = blockIdx.x * 256 + threadIdx.x;
    if (g < 16384) {
        short8 o;
        if (g < 4096) {               // preW: A|B halves of eW1, n col-permuted
            int u = g, nt = u >> 8, rem = u & 255;
            int kc = rem >> 6, lane = rem & 63;
            int n  = nt * 16 + (lane & 15);
            int kb = kc * 32 + ((lane >> 4) & 3) * 8;
#pragma unroll
            for (int j = 0; j < 8; ++j) {
                int k = kb + j;
                float v = (n < 128) ? eW1[(long)k * HID + permk(n)]
                                    : eW1[(long)(128 + k) * HID + permk(n - 128)];
                o[j] = (short)f2bf(v);
            }
        } else {
            const float* src; int u, KC, mode;
            if (g < 6144)       { src = eW2; u = g - 4096;  KC = 4;  mode = 1; }
            else if (g < 8192)  { src = cW1; u = g - 6144;  KC = 4;  mode = 1; }
            else if (g < 14336) { src = nW1; u = g - 8192;  KC = 12; mode = 2; }
            else                { src = nW2; u = g - 14336; KC = 4;  mode = 1; }
            int nt = u / (KC * 64), rem = u % (KC * 64);
            int kc = rem >> 6, lane = rem & 63;
            int n  = nt * 16 + (lane & 15);
            int kb = kc * 32 + ((lane >> 4) & 3) * 8;
#pragma unroll
            for (int j = 0; j < 8; ++j) {
                int k = kb + j;
                int ks;
                if (mode == 1) ks = permk(k);
                else {         // nW1: h natural, agg hi/lo permuted (lo reuses rows)
                    if (k < 128)      ks = k;
                    else if (k < 256) ks = 128 + permk(k - 128);
                    else              ks = 128 + permk(k - 256);
                }
                o[j] = (short)f2bf(src[(long)ks * HID + n]);
            }
        }
        *(short8*)&wsw[(long)g * 8] = o;
    } else if (g < 16640) {
        int i = g - 16384;
        if (i < 128) wrn[i] = eW1[(long)256 * HID + permk(i)];
        else         wea[i - 128] = eW1[(long)257 * HID + permk(i - 128)];
    } else if (g < 16640 + 1600000) {                  // zero agg region
        long i = (long)(g - 16640);
        ((float4*)out)[i] = make_float4(0.f, 0.f, 0.f, 0.f);
    } else if (g < 16640 + 1600000 + 150000) {         // pos -> outpos
        int i = g - 16640 - 1600000;
        out[(long)NNODE * HID + i] = pos[i];
    } else if (g < 16640 + 1600000 + 150000 + 50000) { // zero deg
        int i = g - 16640 - 1600000 - 150000;
        deg[i] = 0;
    }
}

// ------------------------------------------------------------------ pre: A|B = h@eW1 halves (+eb1), bf16 physical order
__global__ __launch_bounds__(256)
void egnn_pre(const float* h, const float* eb1, const short* preW, short* AB)
{
    __shared__ __align__(16) short sH[EB * PX];
    const int t  = threadIdx.x;
    const int n0 = blockIdx.x * EB;

    for (int i = t; i < EB * 16; i += 256) {
        int e = i >> 4, c16 = i & 15;
        int nd = n0 + e; if (nd >= NNODE) nd = NNODE - 1;
        const float4 v0 = *(const float4*)&h[(long)nd * HID + c16 * 8];
        const float4 v1 = *(const float4*)&h[(long)nd * HID + c16 * 8 + 4];
        uint4 o;
        o.x = pkbf(make_float2(v0.x, v0.y)); o.y = pkbf(make_float2(v0.z, v0.w));
        o.z = pkbf(make_float2(v1.x, v1.y)); o.w = pkbf(make_float2(v1.z, v1.w));
        *(uint4*)&sH[e * PX + c16 * 8] = o;
    }
    __syncthreads();

    const int lane = t & 63, w = t >> 6, l15 = lane & 15, q = lane >> 4;
    f32x4 acc[4][4];   // [nt][mt]
    short8 a[4];
#pragma unroll
    for (int nt = 0; nt < 4; ++nt) {
        int n = w * 64 + nt * 16 + l15;
        float bv = (n < 128) ? eb1[permk(n)] : 0.0f;
#pragma unroll
        for (int mt = 0; mt < 4; ++mt)
            for (int r = 0; r < 4; ++r) acc[nt][mt][r] = bv;
    }
    for (int kc = 0; kc < 4; ++kc) {
#pragma unroll
        for (int mt = 0; mt < 4; ++mt)
            a[mt] = *(const short8*)&sH[(mt * 16 + l15) * PX + kc * 32 + q * 8];
#pragma unroll
        for (int nt = 0; nt < 4; ++nt) {
            short8 b = *(const short8*)&preW[(((w * 4 + nt) * 4 + kc) * 64 + lane) * 8];
#pragma unroll
            for (int mt = 0; mt < 4; ++mt)
                acc[nt][mt] = __builtin_amdgcn_mfma_f32_16x16x32_bf16(a[mt], b, acc[nt][mt], 0, 0, 0);
        }
    }
#pragma unroll
    for (int nt = 0; nt < 4; ++nt)
#pragma unroll
        for (int mt = 0; mt < 4; ++mt)
            for (int r = 0; r < 4; ++r) {
                int nd = n0 + mt * 16 + q * 4 + r;
                if (nd < NNODE)
                    AB[(long)nd * 256 + w * 64 + nt * 16 + l15] = (short)f2bf(acc[nt][mt][r]);
            }
}

// ------------------------------------------------------------------ CSR build
__global__ void egnn_hist(const int* eidx, int* deg)
{
    int i = blockIdx.x * 256 + threadIdx.x;
    if (i < NEDGE / 4) {
        int4 v = ((const int4*)eidx)[i];
        atomicAdd(&deg[v.x], 1); atomicAdd(&deg[v.y], 1);
        atomicAdd(&deg[v.z], 1); atomicAdd(&deg[v.w], 1);
    }
}
__global__ void egnn_scan1(const int* deg, int* rowptr, int* bsum)
{
    __shared__ int s[256];
    int t = threadIdx.x, i = blockIdx.x * 256 + t;
    int v = (i < NNODE) ? deg[i] : 0;
    s[t] = v; __syncthreads();
    for (int o = 1; o < 256; o <<= 1) {
        int x = (t >= o) ? s[t - o] : 0;
        __syncthreads(); s[t] += x; __syncthreads();
    }
    if (i < NNODE) rowptr[i] = s[t] - v;
    if (t == 255) bsum[blockIdx.x] = s[t];
}
__global__ void egnn_scanF(int* rowptr, const int* bsum, int* cursor)
{
    __shared__ int red[256];
    int t = threadIdx.x, b = blockIdx.x;
    int acc = 0;
    for (int i = t; i < b; i += 256) acc += bsum[i];
    red[t] = acc; __syncthreads();
    for (int o = 128; o > 0; o >>= 1) {
        if (t < o) red[t] += red[t + o];
        __syncthreads();
    }
    int i = b * 256 + t;
    if (i < NNODE) cursor[i] = rowptr[i] + red[0];
}
__global__ void egnn_scatter(const int* eidx, int* cursor, int* perm)
{
    int e = blockIdx.x * 256 + threadIdx.x;
    if (e < NEDGE) {
        int p = atomicAdd(&cursor[eidx[e]], 1);
        perm[p] = e;
    }
}

// ------------------------------------------------------------------ edge phase (4 barriers)
__global__ __launch_bounds__(256, 4)
void egnn_edge(const short* AB, const float* pos, const float* ea, const int* eidx,
               const int* perm, const float* wrn, const float* wea,
               const float* eb2, const float* cb1, const float* cW2, const float* cb2,
               const short* eW2f, const short* cW1f,
               float* aggout, float* outpos)
{
    __shared__ __align__(16) short sX[EB * PX];   // bf16 m -> fp32 m (cols 0-63)
    __shared__ __align__(16) short sB[EB * PX];   // silu(L1) -> fp32 m (cols 64-127)
    __shared__ int   rci[2 * EB];
    __shared__ float rad[EB][4];
    __shared__ float part[EB][4];

    const int t  = threadIdx.x;
    const int e0 = blockIdx.x * EB;
    const int lane = t & 63;
    const int w    = t >> 6;
    const int l15  = lane & 15;
    const int q    = lane >> 4;
    const int ns   = w * 32;

    short8 bb[4][2];
    short8 a[4];
    f32x4 acc[2][4];
    float2 mreg2[4][4];

    // P0 (t<64): index table + geometry for later phases
    if (t < EB) {
        int e = perm[e0 + t];
        int r = eidx[e], c = eidx[NEDGE + e];
        rci[t] = r; rci[EB + t] = c;
        float dx = pos[(long)r * 3 + 0] - pos[(long)c * 3 + 0];
        float dy = pos[(long)r * 3 + 1] - pos[(long)c * 3 + 1];
        float dz = pos[(long)r * 3 + 2] - pos[(long)c * 3 + 2];
        float rn = fmaxf(sqrtf(dx * dx + dy * dy + dz * dz), 1e-8f);
        rad[t][0] = dx; rad[t][1] = dy; rad[t][2] = dz; rad[t][3] = rn;
    }

    // P1: gather A[row]+B[col], add rn/ea rank-2 update (fp32), silu -> sB (physical cols)
    {
        const int e = t >> 2, g = t & 3;
        const int pe  = perm[e0 + e];
        const int row = eidx[pe];
        const int col = eidx[NEDGE + pe];
        const float eav = ea[pe];
        float dx = pos[(long)row * 3 + 0] - pos[(long)col * 3 + 0];
        float dy = pos[(long)row * 3 + 1] - pos[(long)col * 3 + 1];
        float dz = pos[(long)row * 3 + 2] - pos[(long)col * 3 + 2];
        float rn = fmaxf(sqrtf(dx * dx + dy * dy + dz * dz), 1e-8f);
        const uint4* Ap = (const uint4*)&AB[(long)row * 256 + g * 32];
        const uint4* Bp = (const uint4*)&AB[(long)col * 256 + 128 + g * 32];
        uint4 av[4], bv[4];
#pragma unroll
        for (int c4 = 0; c4 < 4; ++c4) { av[c4] = Ap[c4]; bv[c4] = Bp[c4]; }
        const float4* wr4 = (const float4*)&wrn[g * 32];
        const float4* we4 = (const float4*)&wea[g * 32];
#pragma unroll
        for (int c4 = 0; c4 < 4; ++c4) {
            float4 w0 = wr4[c4 * 2], w1 = wr4[c4 * 2 + 1];
            float4 u0 = we4[c4 * 2], u1 = we4[c4 * 2 + 1];
            const unsigned int* au = (const unsigned int*)&av[c4];
            const unsigned int* bu = (const unsigned int*)&bv[c4];
            unsigned int pk[4];
            float wl[8] = {w0.x, w0.y, w0.z, w0.w, w1.x, w1.y, w1.z, w1.w};
            float ul[8] = {u0.x, u0.y, u0.z, u0.w, u1.x, u1.y, u1.z, u1.w};
#pragma unroll
            for (int p = 0; p < 4; ++p) {
                float x = bf2f((unsigned short)au[p]) + bf2f((unsigned short)bu[p])
                        + rn * wl[p * 2] + eav * ul[p * 2];
                float y = bf2f((unsigned short)(au[p] >> 16)) + bf2f((unsigned short)(bu[p] >> 16))
                        + rn * wl[p * 2 + 1] + eav * ul[p * 2 + 1];
                pk[p] = pkbf(silu2(x, y));
            }
            *(uint4*)&sB[e * PX + g * 32 + c4 * 8] = make_uint4(pk[0], pk[1], pk[2], pk[3]);
        }
    }
    // preload GEMM2 B-frags (issue before barrier)
#pragma unroll
    for (int kc = 0; kc < 4; ++kc)
#pragma unroll
        for (int nt = 0; nt < 2; ++nt)
            bb[kc][nt] = *(const short8*)&eW2f[(((w * 2 + nt) * 4 + kc) * 64 + lane) * 8];
    __syncthreads();   // B1

    // P2: GEMM2: sB @ eW2f -> silu = m (float2 regs + interleaved bf16 into sX)
#pragma unroll
    for (int nt = 0; nt < 2; ++nt) {
        float bv = eb2[ns + nt * 16 + l15];
#pragma unroll
        for (int mt = 0; mt < 4; ++mt)
            for (int r = 0; r < 4; ++r) acc[nt][mt][r] = bv;
    }
#pragma unroll
    for (int kc = 0; kc < 4; ++kc) {
#pragma unroll
        for (int mt = 0; mt < 4; ++mt)
            a[mt] = *(const short8*)&sB[(mt * 16 + l15) * PX + kc * 32 + q * 8];
#pragma unroll
        for (int nt = 0; nt < 2; ++nt)
#pragma unroll
            for (int mt = 0; mt < 4; ++mt)
                acc[nt][mt] = __builtin_amdgcn_mfma_f32_16x16x32_bf16(a[mt], bb[kc][nt], acc[nt][mt], 0, 0, 0);
    }
    // preload GEMM3 B-frags
#pragma unroll
    for (int kc = 0; kc < 4; ++kc)
#pragma unroll
        for (int nt = 0; nt < 2; ++nt)
            bb[kc][nt] = *(const short8*)&cW1f[(((w * 2 + nt) * 4 + kc) * 64 + lane) * 8];
#pragma unroll
    for (int mt = 0; mt < 4; ++mt)
#pragma unroll
        for (int r = 0; r < 4; ++r) {
            float2 v = silu2(acc[0][mt][r], acc[1][mt][r]);
            mreg2[mt][r] = v;
            *(unsigned int*)&sX[(mt * 16 + q * 4 + r) * PX + ns + 2 * l15] = pkbf(v);
        }
    __syncthreads();   // B2

    // P3: GEMM3: m @ cW1f -> silu -> dot(cW2) -> part
#pragma unroll
    for (int nt = 0; nt < 2; ++nt) {
        float bv = cb1[ns + nt * 16 + l15];
#pragma unroll
        for (int mt = 0; mt < 4; ++mt)
            for (int r = 0; r < 4; ++r) acc[nt][mt][r] = bv;
    }
#pragma unroll
    for (int kc = 0; kc < 4; ++kc) {
#pragma unroll
        for (int mt = 0; mt < 4; ++mt)
            a[mt] = *(const short8*)&sX[(mt * 16 + l15) * PX + kc * 32 + q * 8];
#pragma unroll
        for (int nt = 0; nt < 2; ++nt)
#pragma unroll
            for (int mt = 0; mt < 4; ++mt)
                acc[nt][mt] = __builtin_amdgcn_mfma_f32_16x16x32_bf16(a[mt], bb[kc][nt], acc[nt][mt], 0, 0, 0);
    }
    {
        float cw0 = cW2[ns + l15];
        float cw1 = cW2[ns + 16 + l15];
#pragma unroll
        for (int mt = 0; mt < 4; ++mt) {
            float p[4];
            for (int r = 0; r < 4; ++r) {
                float2 s = silu2(acc[0][mt][r], acc[1][mt][r]);
                p[r] = s.x * cw0 + s.y * cw1;
            }
            for (int mask = 1; mask < 16; mask <<= 1)
                for (int r = 0; r < 4; ++r) p[r] += __shfl_xor(p[r], mask);
            if (l15 == 0)
                for (int r = 0; r < 4; ++r) part[mt * 16 + q * 4 + r][w] = p[r];
        }
    }
    __syncthreads();   // B3 (sX/sB reads done -> dump may overwrite)

    // P4: fp32 m dump as float2 (waves 0,1 -> sX, waves 2,3 -> sB) + pos atomics
    {
        float2* dst = (w < 2) ? (float2*)sX : (float2*)sB;
        int cp = w * 16 + l15 - ((w < 2) ? 0 : 32);
#pragma unroll
        for (int mt = 0; mt < 4; ++mt)
#pragma unroll
            for (int r = 0; r < 4; ++r)
                dst[(mt * 16 + q * 4 + r) * 34 + cp] = mreg2[mt][r];
    }
    if (t < EB) {
        float cd  = part[t][0] + part[t][1] + part[t][2] + part[t][3] + cb2[0];
        float inv = cd / rad[t][3];
        int r = rci[t];
        atomicAdd(&outpos[(long)r * 3 + 0], inv * rad[t][0]);
        atomicAdd(&outpos[(long)r * 3 + 1], inv * rad[t][1]);
        atomicAdd(&outpos[(long)r * 3 + 2], inv * rad[t][2]);
    }
    __syncthreads();   // B4

    // P5: run-merged agg atomics: 2 threads/col, 32-edge runs (physical cols)
    {
        int j = t >> 1, k = t & 1;
        const float2* srcf = (j < 64) ? (const float2*)sX : (const float2*)sB;
        int cp = (j & 63) >> 1;
        int comp = j & 1;
        float s = 0.0f;
        int prev = rci[32 * k];
        for (int e = 32 * k; e < 32 * k + 32; ++e) {
            int rr = rci[e];
            if (rr != prev) {
                atomicAdd(&aggout[(long)prev * HID + j], s);
                s = 0.0f; prev = rr;
            }
            float2 v = srcf[e * 34 + cp];
            s += comp ? v.y : v.x;
        }
        atomicAdd(&aggout[(long)prev * HID + j], s);
    }
}

// ------------------------------------------------------------------ node phase (agg aliases out h-region)
__global__ __launch_bounds__(256)
void egnn_node(const float* h, const float* agg,
               const float* nb1, const float* nb2,
               const short* nW1f, const short* nW2f,
               float* out)
{
    __shared__ __align__(16) short sA[EB * PN];
    __shared__ __align__(16) short sB2[EB * PX];

    const int t  = threadIdx.x;
    const int n0 = blockIdx.x * EB;

    for (int i = t; i < EB * 16; i += 256) {     // h -> bf16 inline
        int e = i >> 4, uu = i & 15;
        int nd = n0 + e; if (nd >= NNODE) nd = NNODE - 1;
        const float4 v0 = *(const float4*)&h[(long)nd * HID + uu * 8];
        const float4 v1 = *(const float4*)&h[(long)nd * HID + uu * 8 + 4];
        uint4 o;
        o.x = pkbf(make_float2(v0.x, v0.y)); o.y = pkbf(make_float2(v0.z, v0.w));
        o.z = pkbf(make_float2(v1.x, v1.y)); o.w = pkbf(make_float2(v1.z, v1.w));
        *(uint4*)&sA[e * PN + uu * 8] = o;
    }
    for (int i = t; i < EB * 32; i += 256) {     // agg hi/lo split (physical order)
        int e = i >> 5, uu = i & 31;
        int nd = n0 + e; if (nd >= NNODE) nd = NNODE - 1;
        const float4 v = *(const float4*)&agg[(long)nd * HID + uu * 4];
        unsigned short hx = f2bf(v.x), hy = f2bf(v.y), hz = f2bf(v.z), hw = f2bf(v.w);
        *(uint2*)&sA[e * PN + HID + uu * 4] =
            make_uint2(hx | ((unsigned int)hy << 16), hz | ((unsigned int)hw << 16));
        unsigned int l0 = pkbf(make_float2(v.x - bf2f(hx), v.y - bf2f(hy)));
        unsigned int l1 = pkbf(make_float2(v.z - bf2f(hz), v.w - bf2f(hw)));
        *(uint2*)&sA[e * PN + 2 * HID + uu * 4] = make_uint2(l0, l1);
    }
    __syncthreads();

    const int lane = t & 63;
    const int w    = t >> 6;
    const int l15  = lane & 15;
    const int q    = lane >> 4;
    const int ns   = w * 32;

    f32x4 acc[2][4];
    short8 a[4], b[2];

#pragma unroll
    for (int nt = 0; nt < 2; ++nt) {
        float bv = nb1[ns + nt * 16 + l15];
#pragma unroll
        for (int mt = 0; mt < 4; ++mt)
            for (int r = 0; r < 4; ++r) acc[nt][mt][r] = bv;
    }
    for (int kc = 0; kc < 12; ++kc) {
#pragma unroll
        for (int mt = 0; mt < 4; ++mt)
            a[mt] = *(const short8*)&sA[(mt * 16 + l15) * PN + kc * 32 + q * 8];
#pragma unroll
        for (int nt = 0; nt < 2; ++nt)
            b[nt] = *(const short8*)&nW1f[(((w * 2 + nt) * 12 + kc) * 64 + lane) * 8];
#pragma unroll
        for (int nt = 0; nt < 2; ++nt)
#pragma unroll
            for (int mt = 0; mt < 4; ++mt)
                acc[nt][mt] = __builtin_amdgcn_mfma_f32_16x16x32_bf16(a[mt], b[nt], acc[nt][mt], 0, 0, 0);
    }
#pragma unroll
    for (int mt = 0; mt < 4; ++mt)
#pragma unroll
        for (int r = 0; r < 4; ++r) {
            float2 v = silu2(acc[0][mt][r], acc[1][mt][r]);
            *(unsigned int*)&sB2[(mt * 16 + q * 4 + r) * PX + ns + 2 * l15] = pkbf(v);
        }
    __syncthreads();

#pragma unroll
    for (int nt = 0; nt < 2; ++nt) {
        float bv = nb2[ns + nt * 16 + l15];
#pragma unroll
        for (int mt = 0; mt < 4; ++mt)
            for (int r = 0; r < 4; ++r) acc[nt][mt][r] = bv;
    }
    for (int kc = 0; kc < 4; ++kc) {
#pragma unroll
        for (int mt = 0; mt < 4; ++mt)
            a[mt] = *(const short8*)&sB2[(mt * 16 + l15) * PX + kc * 32 + q * 8];
#pragma unroll
        for (int nt = 0; nt < 2; ++nt)
            b[nt] = *(const short8*)&nW2f[(((w * 2 + nt) * 4 + kc) * 64 + lane) * 8];
#pragma unroll
        for (int nt = 0; nt < 2; ++nt)
#pragma unroll
            for (int mt = 0; mt < 4; ++mt)
                acc[nt][mt] = __builtin_amdgcn_mfma_f32_16x16x32_bf16(a[mt], b[nt], acc[nt][mt], 0, 0, 0);
    }
#pragma unroll
    for (int nt = 0; nt < 2; ++nt)
#pragma unroll
        for (int mt = 0; mt < 4; ++mt)
            for (int r = 0; r < 4; ++r) {
                int m  = mt * 16 + q * 4 + r;
                int nd = n0 + m;
                if (nd < NNODE) {
                    int n = ns + nt * 16 + l15;
                    out[(long)nd * HID + n] = h[(long)nd * HID + n] + acc[nt][mt][r];
                }
            }
}

// ------------------------------------------------------------------ launch
extern "C" void kernel_launch(void* const* d_in, const int* in_sizes, int n_in,
                              void* d_out, int out_size, void* d_ws, size_t ws_size,
                              hipStream_t stream)
{
    const float* h    = (const float*)d_in[0];
    const float* pos  = (const float*)d_in[1];
    const float* ea   = (const float*)d_in[2];
    const int*   eidx = (const int*)d_in[3];
    const float* eW1  = (const float*)d_in[4];
    const float* eb1  = (const float*)d_in[5];
    const float* eW2  = (const float*)d_in[6];
    const float* eb2  = (const float*)d_in[7];
    const float* nW1  = (const float*)d_in[8];
    const float* nb1  = (const float*)d_in[9];
    const float* nW2  = (const float*)d_in[10];
    const float* nb2  = (const float*)d_in[11];
    const float* cW1  = (const float*)d_in[12];
    const float* cb1  = (const float*)d_in[13];
    const float* cW2  = (const float*)d_in[14];
    const float* cb2  = (const float*)d_in[15];

    float* out    = (float*)d_out;
    float* outpos = out + (long)NNODE * HID;

    char* ws = (char*)d_ws;
    short* wsw    = (short*)ws;
    float* wrn    = (float*)(ws + WS_WRN);
    float* wea    = (float*)(ws + WS_WEA);
    short* AB     = (short*)(ws + WS_AB);
    int*   deg    = (int*)(ws + WS_DEG);
    int*   rowptr = (int*)(ws + WS_ROW);
    int*   cursor = (int*)(ws + WS_CUR);
    int*   bsum   = (int*)(ws + WS_BSUM);
    int*   perm   = (int*)(ws + WS_PERM);

    const short* preW = wsw;
    const short* eW2f = wsw + 4096 * 8;
    const short* cW1f = wsw + 6144 * 8;
    const short* nW1f = wsw + 8192 * 8;
    const short* nW2f = wsw + 14336 * 8;

    egnn_prep<<<(16640 + 1600000 + 150000 + 50000 + 255) / 256, 256, 0, stream>>>(
        eW1, eW2, cW1, nW1, nW2, pos, wsw, wrn, wea, deg, out);
    egnn_pre<<<(NNODE + EB - 1) / EB, 256, 0, stream>>>(h, eb1, preW, AB);
    egnn_hist<<<(NEDGE / 4 + 255) / 256, 256, 0, stream>>>(eidx, deg);
    egnn_scan1<<<196, 256, 0, stream>>>(deg, rowptr, bsum);
    egnn_scanF<<<196, 256, 0, stream>>>(rowptr, bsum, cursor);
    egnn_scatter<<<(NEDGE + 255) / 256, 256, 0, stream>>>(eidx, cursor, perm);
    egnn_edge<<<NEDGE / EB, 256, 0, stream>>>(AB, pos, ea, eidx, perm, wrn, wea,
                                              eb2, cb1, cW2, cb2,
                                              eW2f, cW1f, out, outpos);
    egnn_node<<<(NNODE + EB - 1) / EB, 256, 0, stream>>>(h, out, nb1, nb2,
                                                         nW1f, nW2f, out);
}

// Round 8
// 545.077 us; speedup vs baseline: 1.0410x; 1.0410x over previous
//
#include <hip/hip_runtime.h>
#include <hip/hip_bf16.h>
#include <math.h>

#define HID   128
#define NNODE 50000
#define NEDGE 800000
#define EB    64
#define PX    136   // intermediate pitch (shorts) = 68 dwords
#define PN    392   // node featA pitch (shorts): [h | agg_hi | agg_lo]

typedef __attribute__((ext_vector_type(8))) short short8;
typedef __attribute__((ext_vector_type(4))) float f32x4;

__device__ __forceinline__ float2 silu2(float x, float y) {
    return make_float2(x * __builtin_amdgcn_rcpf(1.0f + __expf(-x)),
                       y * __builtin_amdgcn_rcpf(1.0f + __expf(-y)));
}
__device__ __forceinline__ unsigned int pkbf(float2 v) {   // packed RNE f32x2 -> bf16x2
    __hip_bfloat162 b2 = __float22bfloat162_rn(v);
    return *(unsigned int*)&b2;
}
__device__ __forceinline__ unsigned short f2bf(float f) {  // scalar RNE
    unsigned int u = __float_as_uint(f);
    u += 0x7FFFu + ((u >> 16) & 1u);
    return (unsigned short)(u >> 16);
}
__device__ __forceinline__ float bf2f(unsigned short s) {
    return __uint_as_float(((unsigned int)s) << 16);
}
// physical col p (128-wide pair-interleaved buffer) -> logical col
__device__ __forceinline__ int permk(int p) {
    return (p & ~31) | ((p & 31) >> 1) | ((p & 1) << 4);
}

// ws layout (bytes)
#define WS_WRN  262144
#define WS_WEA  262656
#define WS_AB   263168
#define WS_DEG  25863168
#define WS_ROW  26063168
#define WS_CUR  26263168
#define WS_BSUM 26463168
#define WS_PERM 26464192

// ------------------------------------------------------------------ prep
__global__ void egnn_prep(const float* eW1, const float* eW2, const float* cW1,
                          const float* nW1, const float* nW2, const float* pos,
                          short* wsw, float* wrn, float* wea, int* deg, float* out)
{
    int g = blockIdx.x * 256 + threadIdx.x;
    if (g < 16384) {
        short8 o;
        if (g < 4096) {               // preW: A|B halves of eW1, n col-permuted
            int u = g, nt = u >> 8, rem = u & 255;
            int kc = rem >> 6, lane = rem & 63;
            int n  = nt * 16 + (lane & 15);
            int kb = kc * 32 + ((lane >> 4) & 3) * 8;
#pragma unroll
            for (int j = 0; j < 8; ++j) {
                int k = kb + j;
                float v = (n < 128) ? eW1[(long)k * HID + permk(n)]
                                    : eW1[(long)(128 + k) * HID + permk(n - 128)];
                o[j] = (short)f2bf(v);
            }
        } else {
            const float* src; int u, KC, mode;
            if (g < 6144)       { src = eW2; u = g - 4096;  KC = 4;  mode = 1; }
            else if (g < 8192)  { src = cW1; u = g - 6144;  KC = 4;  mode = 1; }
            else if (g < 14336) { src = nW1; u = g - 8192;  KC = 12; mode = 2; }
            else                { src = nW2; u = g - 14336; KC = 4;  mode = 1; }
            int nt = u / (KC * 64), rem = u % (KC * 64);
            int kc = rem >> 6, lane = rem & 63;
            int n  = nt * 16 + (lane & 15);
            int kb = kc * 32 + ((lane >> 4) & 3) * 8;
#pragma unroll
            for (int j = 0; j < 8; ++j) {
                int k = kb + j;
                int ks;
                if (mode == 1) ks = permk(k);
                else {         // nW1: h natural, agg hi/lo permuted (lo reuses rows)
                    if (k < 128)      ks = k;
                    else if (k < 256) ks = 128 + permk(k - 128);
                    else              ks = 128 + permk(k - 256);
                }
                o[j] = (short)f2bf(src[(long)ks * HID + n]);
            }
        }
        *(short8*)&wsw[(long)g * 8] = o;
    } else if (g < 16640) {
        int i = g - 16384;
        if (i < 128) wrn[i] = eW1[(long)256 * HID + permk(i)];
        else         wea[i - 128] = eW1[(long)257 * HID + permk(i - 128)];
    } else if (g < 16640 + 1600000) {                  // zero agg region
        long i = (long)(g - 16640);
        ((float4*)out)[i] = make_float4(0.f, 0.f, 0.f, 0.f);
    } else if (g < 16640 + 1600000 + 150000) {         // pos -> outpos
        int i = g - 16640 - 1600000;
        out[(long)NNODE * HID + i] = pos[i];
    } else if (g < 16640 + 1600000 + 150000 + 50000) { // zero deg
        int i = g - 16640 - 1600000 - 150000;
        deg[i] = 0;
    }
}

// ------------------------------------------------------------------ pre (A|B = h@eW1 + eb1) fused with hist
__global__ __launch_bounds__(256)
void egnn_preh(const float* h, const float* eb1, const short* preW, short* AB,
               const int* eidx, int* deg)
{
    __shared__ __align__(16) short sH[EB * PX];
    if (blockIdx.x >= 782) {     // histogram part (independent work, overlapped)
        int i = (blockIdx.x - 782) * 256 + threadIdx.x;
        if (i < NEDGE / 4) {
            int4 v = ((const int4*)eidx)[i];
            atomicAdd(&deg[v.x], 1); atomicAdd(&deg[v.y], 1);
            atomicAdd(&deg[v.z], 1); atomicAdd(&deg[v.w], 1);
        }
        return;
    }
    const int t  = threadIdx.x;
    const int n0 = blockIdx.x * EB;

    for (int i = t; i < EB * 16; i += 256) {
        int e = i >> 4, c16 = i & 15;
        int nd = n0 + e; if (nd >= NNODE) nd = NNODE - 1;
        const float4 v0 = *(const float4*)&h[(long)nd * HID + c16 * 8];
        const float4 v1 = *(const float4*)&h[(long)nd * HID + c16 * 8 + 4];
        uint4 o;
        o.x = pkbf(make_float2(v0.x, v0.y)); o.y = pkbf(make_float2(v0.z, v0.w));
        o.z = pkbf(make_float2(v1.x, v1.y)); o.w = pkbf(make_float2(v1.z, v1.w));
        *(uint4*)&sH[e * PX + c16 * 8] = o;
    }
    __syncthreads();

    const int lane = t & 63, w = t >> 6, l15 = lane & 15, q = lane >> 4;
    f32x4 acc[4][4];   // [nt][mt]
    short8 a[4];
#pragma unroll
    for (int nt = 0; nt < 4; ++nt) {
        int n = w * 64 + nt * 16 + l15;
        float bv = (n < 128) ? eb1[permk(n)] : 0.0f;
#pragma unroll
        for (int mt = 0; mt < 4; ++mt)
            for (int r = 0; r < 4; ++r) acc[nt][mt][r] = bv;
    }
    for (int kc = 0; kc < 4; ++kc) {
#pragma unroll
        for (int mt = 0; mt < 4; ++mt)
            a[mt] = *(const short8*)&sH[(mt * 16 + l15) * PX + kc * 32 + q * 8];
#pragma unroll
        for (int nt = 0; nt < 4; ++nt) {
            short8 b = *(const short8*)&preW[(((w * 4 + nt) * 4 + kc) * 64 + lane) * 8];
#pragma unroll
            for (int mt = 0; mt < 4; ++mt)
                acc[nt][mt] = __builtin_amdgcn_mfma_f32_16x16x32_bf16(a[mt], b, acc[nt][mt], 0, 0, 0);
        }
    }
#pragma unroll
    for (int nt = 0; nt < 4; ++nt)
#pragma unroll
        for (int mt = 0; mt < 4; ++mt)
            for (int r = 0; r < 4; ++r) {
                int nd = n0 + mt * 16 + q * 4 + r;
                if (nd < NNODE)
                    AB[(long)nd * 256 + w * 64 + nt * 16 + l15] = (short)f2bf(acc[nt][mt][r]);
            }
}

// ------------------------------------------------------------------ CSR scans
__global__ void egnn_scan1(const int* deg, int* rowptr, int* bsum)
{
    __shared__ int s[256];
    int t = threadIdx.x, i = blockIdx.x * 256 + t;
    int v = (i < NNODE) ? deg[i] : 0;
    s[t] = v; __syncthreads();
    for (int o = 1; o < 256; o <<= 1) {
        int x = (t >= o) ? s[t - o] : 0;
        __syncthreads(); s[t] += x; __syncthreads();
    }
    if (i < NNODE) rowptr[i] = s[t] - v;
    if (t == 255) bsum[blockIdx.x] = s[t];
}
__global__ void egnn_scanF(int* rowptr, const int* bsum, int* cursor)
{
    __shared__ int red[256];
    int t = threadIdx.x, b = blockIdx.x;
    int acc = 0;
    for (int i = t; i < b; i += 256) acc += bsum[i];
    red[t] = acc; __syncthreads();
    for (int o = 128; o > 0; o >>= 1) {
        if (t < o) red[t] += red[t + o];
        __syncthreads();
    }
    int i = b * 256 + t;
    if (i < NNODE) cursor[i] = rowptr[i] + red[0];
}
__global__ void egnn_scatter(const int* eidx, int* cursor, int* perm)
{
    int e = blockIdx.x * 256 + threadIdx.x;
    if (e < NEDGE) {
        int p = atomicAdd(&cursor[eidx[e]], 1);
        perm[p] = e;
    }
}

// ------------------------------------------------------------------ edge phase (single main LDS buffer, 6 blocks/CU)
__global__ __launch_bounds__(256, 6)
void egnn_edge(const short* AB, const float* pos, const float* ea, const int* eidx,
               const int* perm, const float* wrn, const float* wea,
               const float* eb2, const float* cb1, const float* cW2, const float* cb2,
               const short* eW2f, const short* cW1f,
               float* aggout, float* outpos)
{
    __shared__ __align__(16) short sB[EB * PX];   // silu(L1) -> bf16 m
    __shared__ int   rci[EB];                     // row index per edge
    __shared__ float rad[EB][4];
    __shared__ float part[EB][4];

    const int t  = threadIdx.x;
    const int e0 = blockIdx.x * EB;
    const int lane = t & 63;
    const int w    = t >> 6;
    const int l15  = lane & 15;
    const int q    = lane >> 4;
    const int ns   = w * 32;

    short8 a[4], b[2];
    f32x4 acc[2][4];

    // P0 (t<64): row table + geometry
    if (t < EB) {
        int e = perm[e0 + t];
        int r = eidx[e], c = eidx[NEDGE + e];
        rci[t] = r;
        float dx = pos[(long)r * 3 + 0] - pos[(long)c * 3 + 0];
        float dy = pos[(long)r * 3 + 1] - pos[(long)c * 3 + 1];
        float dz = pos[(long)r * 3 + 2] - pos[(long)c * 3 + 2];
        float rn = fmaxf(sqrtf(dx * dx + dy * dy + dz * dz), 1e-8f);
        rad[t][0] = dx; rad[t][1] = dy; rad[t][2] = dz; rad[t][3] = rn;
    }

    // P1: gather A[row]+B[col], rank-2 rn/ea update (fp32), silu -> sB (physical cols)
    {
        const int e = t >> 2, g = t & 3;
        const int pe  = perm[e0 + e];
        const int row = eidx[pe];
        const int col = eidx[NEDGE + pe];
        const float eav = ea[pe];
        float dx = pos[(long)row * 3 + 0] - pos[(long)col * 3 + 0];
        float dy = pos[(long)row * 3 + 1] - pos[(long)col * 3 + 1];
        float dz = pos[(long)row * 3 + 2] - pos[(long)col * 3 + 2];
        float rn = fmaxf(sqrtf(dx * dx + dy * dy + dz * dz), 1e-8f);
        const uint4* Ap = (const uint4*)&AB[(long)row * 256 + g * 32];
        const uint4* Bp = (const uint4*)&AB[(long)col * 256 + 128 + g * 32];
        uint4 av[4], bv[4];
#pragma unroll
        for (int c4 = 0; c4 < 4; ++c4) { av[c4] = Ap[c4]; bv[c4] = Bp[c4]; }
        const float4* wr4 = (const float4*)&wrn[g * 32];
        const float4* we4 = (const float4*)&wea[g * 32];
#pragma unroll
        for (int c4 = 0; c4 < 4; ++c4) {
            float4 w0 = wr4[c4 * 2], w1 = wr4[c4 * 2 + 1];
            float4 u0 = we4[c4 * 2], u1 = we4[c4 * 2 + 1];
            const unsigned int* au = (const unsigned int*)&av[c4];
            const unsigned int* bu = (const unsigned int*)&bv[c4];
            unsigned int pk[4];
            float wl[8] = {w0.x, w0.y, w0.z, w0.w, w1.x, w1.y, w1.z, w1.w};
            float ul[8] = {u0.x, u0.y, u0.z, u0.w, u1.x, u1.y, u1.z, u1.w};
#pragma unroll
            for (int p = 0; p < 4; ++p) {
                float x = bf2f((unsigned short)au[p]) + bf2f((unsigned short)bu[p])
                        + rn * wl[p * 2] + eav * ul[p * 2];
                float y = bf2f((unsigned short)(au[p] >> 16)) + bf2f((unsigned short)(bu[p] >> 16))
                        + rn * wl[p * 2 + 1] + eav * ul[p * 2 + 1];
                pk[p] = pkbf(silu2(x, y));
            }
            *(uint4*)&sB[e * PX + g * 32 + c4 * 8] = make_uint4(pk[0], pk[1], pk[2], pk[3]);
        }
    }
    __syncthreads();   // B1

    // P2: GEMM2: sB @ eW2f
#pragma unroll
    for (int nt = 0; nt < 2; ++nt) {
        float bv = eb2[ns + nt * 16 + l15];
#pragma unroll
        for (int mt = 0; mt < 4; ++mt)
            for (int r = 0; r < 4; ++r) acc[nt][mt][r] = bv;
    }
#pragma unroll
    for (int kc = 0; kc < 4; ++kc) {
#pragma unroll
        for (int mt = 0; mt < 4; ++mt)
            a[mt] = *(const short8*)&sB[(mt * 16 + l15) * PX + kc * 32 + q * 8];
#pragma unroll
        for (int nt = 0; nt < 2; ++nt)
            b[nt] = *(const short8*)&eW2f[(((w * 2 + nt) * 4 + kc) * 64 + lane) * 8];
#pragma unroll
        for (int nt = 0; nt < 2; ++nt)
#pragma unroll
            for (int mt = 0; mt < 4; ++mt)
                acc[nt][mt] = __builtin_amdgcn_mfma_f32_16x16x32_bf16(a[mt], b[nt], acc[nt][mt], 0, 0, 0);
    }
    __syncthreads();   // B2: all GEMM2 reads of sB complete

    // m = silu(GEMM2) -> overwrite sB (bf16, physical pairs)
#pragma unroll
    for (int mt = 0; mt < 4; ++mt)
#pragma unroll
        for (int r = 0; r < 4; ++r) {
            float2 v = silu2(acc[0][mt][r], acc[1][mt][r]);
            *(unsigned int*)&sB[(mt * 16 + q * 4 + r) * PX + ns + 2 * l15] = pkbf(v);
        }
    __syncthreads();   // B3

    // P3: GEMM3: m @ cW1f -> silu -> dot(cW2) -> part
#pragma unroll
    for (int nt = 0; nt < 2; ++nt) {
        float bv = cb1[ns + nt * 16 + l15];
#pragma unroll
        for (int mt = 0; mt < 4; ++mt)
            for (int r = 0; r < 4; ++r) acc[nt][mt][r] = bv;
    }
#pragma unroll
    for (int kc = 0; kc < 4; ++kc) {
#pragma unroll
        for (int mt = 0; mt < 4; ++mt)
            a[mt] = *(const short8*)&sB[(mt * 16 + l15) * PX + kc * 32 + q * 8];
#pragma unroll
        for (int nt = 0; nt < 2; ++nt)
            b[nt] = *(const short8*)&cW1f[(((w * 2 + nt) * 4 + kc) * 64 + lane) * 8];
#pragma unroll
        for (int nt = 0; nt < 2; ++nt)
#pragma unroll
            for (int mt = 0; mt < 4; ++mt)
                acc[nt][mt] = __builtin_amdgcn_mfma_f32_16x16x32_bf16(a[mt], b[nt], acc[nt][mt], 0, 0, 0);
    }
    {
        float cw0 = cW2[ns + l15];
        float cw1 = cW2[ns + 16 + l15];
#pragma unroll
        for (int mt = 0; mt < 4; ++mt) {
            float p[4];
            for (int r = 0; r < 4; ++r) {
                float2 s = silu2(acc[0][mt][r], acc[1][mt][r]);
                p[r] = s.x * cw0 + s.y * cw1;
            }
            for (int mask = 1; mask < 16; mask <<= 1)
                for (int r = 0; r < 4; ++r) p[r] += __shfl_xor(p[r], mask);
            if (l15 == 0)
                for (int r = 0; r < 4; ++r) part[mt * 16 + q * 4 + r][w] = p[r];
        }
    }
    __syncthreads();   // B4: part visible; sB (m) untouched since B3

    // P4: pos atomics (t<64)
    if (t < EB) {
        float cd  = part[t][0] + part[t][1] + part[t][2] + part[t][3] + cb2[0];
        float inv = cd / rad[t][3];
        int r = rci[t];
        atomicAdd(&outpos[(long)r * 3 + 0], inv * rad[t][0]);
        atomicAdd(&outpos[(long)r * 3 + 1], inv * rad[t][1]);
        atomicAdd(&outpos[(long)r * 3 + 2], inv * rad[t][2]);
    }

    // P5: run-merged agg atomics reading bf16 m from sB (1 thread/col x 2 halves)
    {
        int j = t >> 1, k = t & 1;                 // physical col j, edge half k
        float s = 0.0f;
        int prev = rci[32 * k];
        for (int e = 32 * k; e < 32 * k + 32; ++e) {
            int rr = rci[e];
            if (rr != prev) {
                atomicAdd(&aggout[(long)prev * HID + j], s);
                s = 0.0f; prev = rr;
            }
            s += bf2f(*(const unsigned short*)&sB[e * PX + j]);
        }
        atomicAdd(&aggout[(long)prev * HID + j], s);
    }
}

// ------------------------------------------------------------------ node phase (agg aliases out h-region)
__global__ __launch_bounds__(256)
void egnn_node(const float* h, const float* agg,
               const float* nb1, const float* nb2,
               const short* nW1f, const short* nW2f,
               float* out)
{
    __shared__ __align__(16) short sA[EB * PN];
    __shared__ __align__(16) short sB2[EB * PX];

    const int t  = threadIdx.x;
    const int n0 = blockIdx.x * EB;

    for (int i = t; i < EB * 16; i += 256) {     // h -> bf16 inline
        int e = i >> 4, uu = i & 15;
        int nd = n0 + e; if (nd >= NNODE) nd = NNODE - 1;
        const float4 v0 = *(const float4*)&h[(long)nd * HID + uu * 8];
        const float4 v1 = *(const float4*)&h[(long)nd * HID + uu * 8 + 4];
        uint4 o;
        o.x = pkbf(make_float2(v0.x, v0.y)); o.y = pkbf(make_float2(v0.z, v0.w));
        o.z = pkbf(make_float2(v1.x, v1.y)); o.w = pkbf(make_float2(v1.z, v1.w));
        *(uint4*)&sA[e * PN + uu * 8] = o;
    }
    for (int i = t; i < EB * 32; i += 256) {     // agg hi/lo split (physical order)
        int e = i >> 5, uu = i & 31;
        int nd = n0 + e; if (nd >= NNODE) nd = NNODE - 1;
        const float4 v = *(const float4*)&agg[(long)nd * HID + uu * 4];
        unsigned short hx = f2bf(v.x), hy = f2bf(v.y), hz = f2bf(v.z), hw = f2bf(v.w);
        *(uint2*)&sA[e * PN + HID + uu * 4] =
            make_uint2(hx | ((unsigned int)hy << 16), hz | ((unsigned int)hw << 16));
        unsigned int l0 = pkbf(make_float2(v.x - bf2f(hx), v.y - bf2f(hy)));
        unsigned int l1 = pkbf(make_float2(v.z - bf2f(hz), v.w - bf2f(hw)));
        *(uint2*)&sA[e * PN + 2 * HID + uu * 4] = make_uint2(l0, l1);
    }
    __syncthreads();

    const int lane = t & 63;
    const int w    = t >> 6;
    const int l15  = lane & 15;
    const int q    = lane >> 4;
    const int ns   = w * 32;

    f32x4 acc[2][4];
    short8 a[4], b[2];

#pragma unroll
    for (int nt = 0; nt < 2; ++nt) {
        float bv = nb1[ns + nt * 16 + l15];
#pragma unroll
        for (int mt = 0; mt < 4; ++mt)
            for (int r = 0; r < 4; ++r) acc[nt][mt][r] = bv;
    }
    for (int kc = 0; kc < 12; ++kc) {
#pragma unroll
        for (int mt = 0; mt < 4; ++mt)
            a[mt] = *(const short8*)&sA[(mt * 16 + l15) * PN + kc * 32 + q * 8];
#pragma unroll
        for (int nt = 0; nt < 2; ++nt)
            b[nt] = *(const short8*)&nW1f[(((w * 2 + nt) * 12 + kc) * 64 + lane) * 8];
#pragma unroll
        for (int nt = 0; nt < 2; ++nt)
#pragma unroll
            for (int mt = 0; mt < 4; ++mt)
                acc[nt][mt] = __builtin_amdgcn_mfma_f32_16x16x32_bf16(a[mt], b[nt], acc[nt][mt], 0, 0, 0);
    }
#pragma unroll
    for (int mt = 0; mt < 4; ++mt)
#pragma unroll
        for (int r = 0; r < 4; ++r) {
            float2 v = silu2(acc[0][mt][r], acc[1][mt][r]);
            *(unsigned int*)&sB2[(mt * 16 + q * 4 + r) * PX + ns + 2 * l15] = pkbf(v);
        }
    __syncthreads();

#pragma unroll
    for (int nt = 0; nt < 2; ++nt) {
        float bv = nb2[ns + nt * 16 + l15];
#pragma unroll
        for (int mt = 0; mt < 4; ++mt)
            for (int r = 0; r < 4; ++r) acc[nt][mt][r] = bv;
    }
    for (int kc = 0; kc < 4; ++kc) {
#pragma unroll
        for (int mt = 0; mt < 4; ++mt)
            a[mt] = *(const short8*)&sB2[(mt * 16 + l15) * PX + kc * 32 + q * 8];
#pragma unroll
        for (int nt = 0; nt < 2; ++nt)
            b[nt] = *(const short8*)&nW2f[(((w * 2 + nt) * 4 + kc) * 64 + lane) * 8];
#pragma unroll
        for (int nt = 0; nt < 2; ++nt)
#pragma unroll
            for (int mt = 0; mt < 4; ++mt)
                acc[nt][mt] = __builtin_amdgcn_mfma_f32_16x16x32_bf16(a[mt], b[nt], acc[nt][mt], 0, 0, 0);
    }
#pragma unroll
    for (int nt = 0; nt < 2; ++nt)
#pragma unroll
        for (int mt = 0; mt < 4; ++mt)
            for (int r = 0; r < 4; ++r) {
                int m  = mt * 16 + q * 4 + r;
                int nd = n0 + m;
                if (nd < NNODE) {
                    int n = ns + nt * 16 + l15;
                    out[(long)nd * HID + n] = h[(long)nd * HID + n] + acc[nt][mt][r];
                }
            }
}

// ------------------------------------------------------------------ launch
extern "C" void kernel_launch(void* const* d_in, const int* in_sizes, int n_in,
                              void* d_out, int out_size, void* d_ws, size_t ws_size,
                              hipStream_t stream)
{
    const float* h    = (const float*)d_in[0];
    const float* pos  = (const float*)d_in[1];
    const float* ea   = (const float*)d_in[2];
    const int*   eidx = (const int*)d_in[3];
    const float* eW1  = (const float*)d_in[4];
    const float* eb1  = (const float*)d_in[5];
    const float* eW2  = (const float*)d_in[6];
    const float* eb2  = (const float*)d_in[7];
    const float* nW1  = (const float*)d_in[8];
    const float* nb1  = (const float*)d_in[9];
    const float* nW2  = (const float*)d_in[10];
    const float* nb2  = (const float*)d_in[11];
    const float* cW1  = (const float*)d_in[12];
    const float* cb1  = (const float*)d_in[13];
    const float* cW2  = (const float*)d_in[14];
    const float* cb2  = (const float*)d_in[15];

    float* out    = (float*)d_out;
    float* outpos = out + (long)NNODE * HID;

    char* ws = (char*)d_ws;
    short* wsw    = (short*)ws;
    float* wrn    = (float*)(ws + WS_WRN);
    float* wea    = (float*)(ws + WS_WEA);
    short* AB     = (short*)(ws + WS_AB);
    int*   deg    = (int*)(ws + WS_DEG);
    int*   rowptr = (int*)(ws + WS_ROW);
    int*   cursor = (int*)(ws + WS_CUR);
    int*   bsum   = (int*)(ws + WS_BSUM);
    int*   perm   = (int*)(ws + WS_PERM);

    const short* preW = wsw;
    const short* eW2f = wsw + 4096 * 8;
    const short* cW1f = wsw + 6144 * 8;
    const short* nW1f = wsw + 8192 * 8;
    const short* nW2f = wsw + 14336 * 8;

    egnn_prep<<<(16640 + 1600000 + 150000 + 50000 + 255) / 256, 256, 0, stream>>>(
        eW1, eW2, cW1, nW1, nW2, pos, wsw, wrn, wea, deg, out);
    egnn_preh<<<782 + 782, 256, 0, stream>>>(h, eb1, preW, AB, eidx, deg);
    egnn_scan1<<<196, 256, 0, stream>>>(deg, rowptr, bsum);
    egnn_scanF<<<196, 256, 0, stream>>>(rowptr, bsum, cursor);
    egnn_scatter<<<(NEDGE + 255) / 256, 256, 0, stream>>>(eidx, cursor, perm);
    egnn_edge<<<NEDGE / EB, 256, 0, stream>>>(AB, pos, ea, eidx, perm, wrn, wea,
                                              eb2, cb1, cW2, cb2,
                                              eW2f, cW1f, out, outpos);
    egnn_node<<<(NNODE + EB - 1) / EB, 256, 0, stream>>>(h, out, nb1, nb2,
                                                         nW1f, nW2f, out);
}